// Round 1
// baseline (125.773 us; speedup 1.0000x reference)
//
#include <hip/hip_runtime.h>
#include <math.h>

#define N_ATOMS    30000
#define N_PAIRS    300000
#define CAP        48              // bucket capacity per atom; multiple of 16
#define NF         64
#define ND         20
#define K_ENV      1280            // 20nu * 64f (packed, no padding)
#define K_TOT      1344            // K_ENV + 64 self features
#define NKSTEP     42              // K_TOT / 32
#define HARD_CUT   6.5f
#define BA         16              // atoms per block in main kernel
#define ESTRIDE    1352            // env row stride in u16 (1344+8 pad -> bank spread)
#define NM1        ((unsigned)(N_ATOMS - 1))

// inverse-distance quantization: invd in [1/6.5, 1/0.85] -> u16
#define INVD_LO    0.15384615385f
#define INVD_RANGE 1.02262443439f
#define QS         (65535.0f / INVD_RANGE)
#define DQ         (INVD_RANGE / 65535.0f)
#define NEXP2      (-0.7213475204444817f)   // -0.5 * log2(e)

typedef short    s16x8  __attribute__((ext_vector_type(8)));
typedef __bf16   bf16x8 __attribute__((ext_vector_type(8)));
typedef unsigned u32x4  __attribute__((ext_vector_type(4)));
typedef float    f32x4  __attribute__((ext_vector_type(4)));
typedef float    f32x16 __attribute__((ext_vector_type(16)));

__device__ __forceinline__ unsigned short f2bf(float x) {
    union { float f; unsigned u; } v; v.f = x;
    unsigned r = v.u + 0x7fffu + ((v.u >> 16) & 1u);   // RNE
    return (unsigned short)(r >> 16);
}
// pack two floats -> packed bf16 pair (a in low 16), RNE
__device__ __forceinline__ unsigned pkbf(float a, float b) {
    return (unsigned)f2bf(a) | ((unsigned)f2bf(b) << 16);
}
// sensitivity for one packed pair-slot, lane's nu.
// w0 = second<<16 | invd_u16 ; lcb = bits of log2(cut) (f32).
// gauss*cut = exp2(-0.5*log2e*z^2 + log2(cut)) -- single transcendental.
__device__ __forceinline__ float senseval(unsigned w0, unsigned lcb, int kidx, int cnt,
                                          float zA, float zB, bool nuok) {
    float uu = (float)(w0 & 0xffffu);
    float z  = __builtin_fmaf(uu, zA, zB);            // z = invd*isig - musig
    float ar = __builtin_fmaf(z * z, NEXP2, __uint_as_float(lcb));
    float e  = __builtin_amdgcn_exp2f(ar);
    return (nuok && kidx < cnt) ? e : 0.0f;           // garbage slots (poison) -> 0
}

// ---------------------------------------------------------------------------
// K0: prep = pack weights into bf16 B-frag layout with phase-1 k'-permutation
// (blocks 0..41), zero cnts (42..159), msr (160), x -> packed-bf16 table
// (161..1098): xb16[a*32+c] = bf16(x[a,2c+1])<<16 | bf16(x[a,2c]).
// Weight perm (verified R9): k'<1280: t=k'/640, g=(k'%640)>>7, c=(k'&127)>>2,
// r=k'&3 -> nu=4g+r, f=2c+t ; k'>=1280: self row, f=k'-1280.
__global__ void k_prep(const float* __restrict__ iw, const float* __restrict__ wself,
                       const float* __restrict__ mu, const float* __restrict__ sigma,
                       const float* __restrict__ x,
                       unsigned short* __restrict__ WtB, int* __restrict__ cnts,
                       float2* __restrict__ msr, unsigned* __restrict__ xb16) {
    if (blockIdx.x < 42) {
        int idx = blockIdx.x * 256 + threadIdx.x;       // (ks*4+q)*64 + lane
        if (idx >= NKSTEP * 4 * 64) return;
        int l  = idx & 63;
        int q  = (idx >> 6) & 3;
        int ks = idx >> 8;
        int n  = q * 16 + (l & 15);
        int kb = ks * 32 + (l >> 4) * 8;
        u32x4 u;
        #pragma unroll
        for (int jj = 0; jj < 4; jj++) {
            unsigned short lo, hi;
            #pragma unroll
            for (int e = 0; e < 2; e++) {
                int k = kb + 2 * jj + e;
                float val;
                if (k < K_ENV) {
                    int t  = k / 640;
                    int rm = k - t * 640;
                    int g  = rm >> 7;
                    int c  = (rm & 127) >> 2;
                    int r  = k & 3;
                    int nu = 4 * g + r;
                    int f  = 2 * c + t;                  // even/odd tile split
                    val = iw[(nu * NF + n) * NF + f];
                } else {
                    val = wself[n * NF + (k - K_ENV)];
                }
                if (e == 0) lo = f2bf(val); else hi = f2bf(val);
            }
            u[jj] = (unsigned)lo | ((unsigned)hi << 16);
        }
        *(u32x4*)&WtB[idx * 8] = u;
    } else if (blockIdx.x < 160) {
        int i = (blockIdx.x - 42) * 256 + threadIdx.x;
        if (i < N_ATOMS) cnts[i] = 0;
    } else if (blockIdx.x == 160) {
        int i = threadIdx.x;
        if (i < ND) { float2 m; m.x = mu[i]; m.y = 1.0f / sigma[i]; msr[i] = m; }
    } else {
        int o = (blockIdx.x - 161) * 256 + threadIdx.x;  // uint4 of xb16
        if (o < N_ATOMS * 32 / 4) {
            int wbase = o * 4;                           // word wi covers floats 2wi,2wi+1
            const float* src = &x[(size_t)wbase * 2];
            float2 f0 = *(const float2*)(src);
            float2 f1 = *(const float2*)(src + 2);
            float2 f2 = *(const float2*)(src + 4);
            float2 f3 = *(const float2*)(src + 6);
            u32x4 u;
            u[0] = pkbf(f0.x, f0.y);
            u[1] = pkbf(f1.x, f1.y);
            u[2] = pkbf(f2.x, f2.y);
            u[3] = pkbf(f3.x, f3.y);
            *(u32x4*)&xb16[wbase] = u;
        }
    }
}

// ---------------------------------------------------------------------------
// K1: scatter pairs into per-atom buckets. Payload 8B/pair:
//   word0 = second<<16 | invd_u16  (inverse distance quantized -> no rcp in K2)
//   word1 = f32 bits of log2(cut(d)) computed ONCE per pair from exact d
//           (was: cos recomputed in all 32 nu-lanes x every K-step in K2).
__global__ void k_scatter(const int* __restrict__ first, const int* __restrict__ second,
                          const float* __restrict__ dist, int* __restrict__ cnts,
                          uint2* __restrict__ pk) {
    int p = (blockIdx.x * 256 + threadIdx.x) * 2;
    if (p >= N_PAIRS) return;
    int2   f2 = *(const int2*)&first[p];
    int2   s2 = *(const int2*)&second[p];
    float2 d2 = *(const float2*)&dist[p];
    {
        float d    = d2.x;
        float invd = 1.0f / d;
        float tq   = fmaxf((invd - INVD_LO) * QS + 0.5f, 0.0f);
        unsigned u = min((unsigned)tq, 65535u);
        float co   = __cosf(0.2416609733530613f * d);    // 0.5*pi/6.5
        float lc   = fmaxf(__log2f(co * co), -10000.0f); // log2(cut); clamp -inf
        int pos = atomicAdd(&cnts[f2.x], 1);
        if (pos < CAP) {
            uint2 v; v.x = ((unsigned)s2.x << 16) | u; v.y = __float_as_uint(lc);
            pk[(size_t)f2.x * CAP + pos] = v;
        }
    }
    {
        float d    = d2.y;
        float invd = 1.0f / d;
        float tq   = fmaxf((invd - INVD_LO) * QS + 0.5f, 0.0f);
        unsigned u = min((unsigned)tq, 65535u);
        float co   = __cosf(0.2416609733530613f * d);
        float lc   = fmaxf(__log2f(co * co), -10000.0f);
        int pos = atomicAdd(&cnts[f2.y], 1);
        if (pos < CAP) {
            uint2 v; v.x = ((unsigned)s2.y << 16) | u; v.y = __float_as_uint(lc);
            pk[(size_t)f2.y * CAP + pos] = v;
        }
    }
}

// ---------------------------------------------------------------------------
// K2: fused sense + MFMA envsum + MFMA interaction matmul. 512 thr = 8 waves.
// R11 loop structure EXACTLY (R9/R12 lesson: cross-atom-loop live values get
// demoted to scratch). All staging in ext-vectors / named scalars.
// Phase 1: wave w handles atoms {2w,2w+1}. Per 16-pair K-step:
//   A = sense^T (8 exp2 inline -- 1 transcendental per element now, rcp/cos
//   precomputed in K1), B = PRE-CONVERTED bf16 x rows via 8 dword gathers
//   (feats {2cl,2cl+1}), combined by single v_perm_b32 ops -> even/odd tiles;
//   2x mfma_f32_32x32x16_bf16; C -> LDS in C-layout.
// Phase 2: waves 0..3: out[16 atoms][64] = env[16][1344] x WtB (16x16x32).
__global__ void __launch_bounds__(512, 6)
k_main(const unsigned* __restrict__ xb16, const int* __restrict__ cnts,
       const uint2* __restrict__ pk, const float2* __restrict__ msr,
       const unsigned short* __restrict__ WtB, const float* __restrict__ bself,
       float* __restrict__ out) {
    __shared__ unsigned short env[BA * ESTRIDE];          // 43264 B -> 3 blocks/CU
    const int t  = threadIdx.x;
    const int w  = t >> 6;       // wave 0..7
    const int l  = t & 63;       // lane
    const int h  = l >> 5;       // half-wave (k-group)
    const int cl = l & 31;       // A: nu row   |  B/C: column
    const int a0 = blockIdx.x * BA;

    // lane-resident sense constants (nu = cl)
    float2 ms   = msr[min(cl, ND - 1)];
    const float isig = ms.y;
    const float zA   = DQ * isig;                         // z = u*zA + zB
    const float zB   = INVD_LO * isig - ms.x * isig;
    const bool  nuok = (cl < ND);
    const unsigned* xw = xb16 + cl;                       // lane's word column

    // hoist both atoms' counts -> the two dependent scalar chains overlap
    const int cntA = min(cnts[a0 + 2 * w + 0], CAP);
    const int cntB = min(cnts[a0 + 2 * w + 1], CAP);

    // ---- Phase 1: MFMA envsum (2 atoms per wave, sequential) ----
    #pragma unroll 1
    for (int ci = 0; ci < 2; ci++) {
        const int i = 2 * w + ci;
        const int a = a0 + i;
        const int cnt = ci ? cntB : cntA;
        const int nst = max((cnt + 15) >> 4, 1);
        const uint2* gb = &pk[(size_t)a * CAP];
        f32x16 acc0 = {0.f}, acc1 = {0.f};
        #pragma unroll 1
        for (int ks = 0; ks < nst; ks++) {
            const int k0 = ks * 16 + h * 8;
            const uint2* bp = gb + k0;                    // 16B-aligned, h-uniform
            uint4 q0 = *(const uint4*)(bp + 0);           // slots k0+0, k0+1
            uint4 q1 = *(const uint4*)(bp + 2);           // slots k0+2, k0+3
            uint4 q2 = *(const uint4*)(bp + 4);
            uint4 q3 = *(const uint4*)(bp + 6);
            // 8 dword gathers of pre-packed bf16 pairs (feats {2cl,2cl+1})
            unsigned g0 = xw[min(q0.x >> 16, NM1) * 32];
            unsigned g1 = xw[min(q0.z >> 16, NM1) * 32];
            unsigned g2 = xw[min(q1.x >> 16, NM1) * 32];
            unsigned g3 = xw[min(q1.z >> 16, NM1) * 32];
            unsigned g4 = xw[min(q2.x >> 16, NM1) * 32];
            unsigned g5 = xw[min(q2.z >> 16, NM1) * 32];
            unsigned g6 = xw[min(q3.x >> 16, NM1) * 32];
            unsigned g7 = xw[min(q3.z >> 16, NM1) * 32];
            u32x4 A, B0, B1;
            A[0] = pkbf(senseval(q0.x, q0.y, k0 + 0, cnt, zA, zB, nuok),
                        senseval(q0.z, q0.w, k0 + 1, cnt, zA, zB, nuok));
            A[1] = pkbf(senseval(q1.x, q1.y, k0 + 2, cnt, zA, zB, nuok),
                        senseval(q1.z, q1.w, k0 + 3, cnt, zA, zB, nuok));
            A[2] = pkbf(senseval(q2.x, q2.y, k0 + 4, cnt, zA, zB, nuok),
                        senseval(q2.z, q2.w, k0 + 5, cnt, zA, zB, nuok));
            A[3] = pkbf(senseval(q3.x, q3.y, k0 + 6, cnt, zA, zB, nuok),
                        senseval(q3.z, q3.w, k0 + 7, cnt, zA, zB, nuok));
            // v_perm lane-combines: low halves = even feats, high = odd feats
            B0[0] = __builtin_amdgcn_perm(g1, g0, 0x05040100u);
            B0[1] = __builtin_amdgcn_perm(g3, g2, 0x05040100u);
            B0[2] = __builtin_amdgcn_perm(g5, g4, 0x05040100u);
            B0[3] = __builtin_amdgcn_perm(g7, g6, 0x05040100u);
            B1[0] = __builtin_amdgcn_perm(g1, g0, 0x07060302u);
            B1[1] = __builtin_amdgcn_perm(g3, g2, 0x07060302u);
            B1[2] = __builtin_amdgcn_perm(g5, g4, 0x07060302u);
            B1[3] = __builtin_amdgcn_perm(g7, g6, 0x07060302u);
            acc0 = __builtin_amdgcn_mfma_f32_32x32x16_bf16(
                       __builtin_bit_cast(bf16x8, A),
                       __builtin_bit_cast(bf16x8, B0), acc0, 0, 0, 0);
            acc1 = __builtin_amdgcn_mfma_f32_32x32x16_bf16(
                       __builtin_bit_cast(bf16x8, A),
                       __builtin_bit_cast(bf16x8, B1), acc1, 0, 0, 0);
        }
        // C -> env LDS. C row = (reg&3)+8*(reg>>2)+4*h; g=2q+h holds rows
        // 4g..4g+3 (g<5 <=> row<20). k' = t*640 + g*128 + cl*4 + r.
        unsigned short* er = &env[i * ESTRIDE];
        #pragma unroll
        for (int q = 0; q < 3; q++) {
            int g = 2 * q + h;
            if (g < 5) {
                uint2 v0, v1;
                v0.x = pkbf(acc0[4 * q + 0], acc0[4 * q + 1]);
                v0.y = pkbf(acc0[4 * q + 2], acc0[4 * q + 3]);
                v1.x = pkbf(acc1[4 * q + 0], acc1[4 * q + 1]);
                v1.y = pkbf(acc1[4 * q + 2], acc1[4 * q + 3]);
                *(uint2*)&er[g * 128 + cl * 4]       = v0;
                *(uint2*)&er[640 + g * 128 + cl * 4] = v1;
            }
        }
        // self features (k'=1280..1343), from the bf16 table
        unsigned sw = xb16[(size_t)a * 32 + (l >> 1)];
        er[K_ENV + l] = (unsigned short)(sw >> ((l & 1) * 16));
    }
    __syncthreads();

    // ---- Phase 2: MFMA GEMM (waves 0..3) ----
    if (w < 4) {
        const int m16  = l & 15;     // atom row / out col
        const int quad = l >> 4;
        f32x4 acc = {0.f, 0.f, 0.f, 0.f};
        for (int ks = 0; ks < NKSTEP; ks++) {
            s16x8 afrag = *(const s16x8*)&env[m16 * ESTRIDE + ks * 32 + quad * 8];
            s16x8 bfrag = *(const s16x8*)&WtB[((ks * 4 + w) * 64 + l) * 8];
            acc = __builtin_amdgcn_mfma_f32_16x16x32_bf16(
                      __builtin_bit_cast(bf16x8, afrag),
                      __builtin_bit_cast(bf16x8, bfrag), acc, 0, 0, 0);
        }
        const float bs = bself[w * 16 + m16];
        #pragma unroll
        for (int r = 0; r < 4; r++) {
            int row = quad * 4 + r;                       // atom within block
            out[(size_t)(a0 + row) * NF + w * 16 + m16] = acc[r] + bs;
        }
    }
}

// ---------------------------------------------------------------------------
extern "C" void kernel_launch(void* const* d_in, const int* in_sizes, int n_in,
                              void* d_out, int out_size, void* d_ws, size_t ws_size,
                              hipStream_t stream) {
    const float* x      = (const float*)d_in[0];
    const int*   first  = (const int*)d_in[1];
    const int*   second = (const int*)d_in[2];
    const float* dist   = (const float*)d_in[3];
    const float* mu     = (const float*)d_in[4];
    const float* sigma  = (const float*)d_in[5];
    const float* iw     = (const float*)d_in[6];
    const float* wself  = (const float*)d_in[7];
    const float* bself  = (const float*)d_in[8];
    float* out = (float*)d_out;

    char* ws = (char*)d_ws;
    unsigned short* WtB  = (unsigned short*)(ws);          // 172032 B
    int*            cnts = (int*)(ws + 172032);            // 120000 B
    float2*         msr  = (float2*)(ws + 292032);         // 160 B
    uint2*          pk   = (uint2*)(ws + 292192);          // 11520000 B
    unsigned*       xb16 = (unsigned*)(ws + 11812192);     // 3840000 B -> ~15.7 MB

    k_prep<<<dim3(161 + (N_ATOMS * 8 + 255) / 256), dim3(256), 0, stream>>>(
        iw, wself, mu, sigma, x, WtB, cnts, msr, xb16);
    k_scatter<<<dim3((N_PAIRS / 2 + 255) / 256), dim3(256), 0, stream>>>(
        first, second, dist, cnts, pk);
    k_main<<<dim3(N_ATOMS / BA), dim3(512), 0, stream>>>(
        xb16, cnts, pk, msr, WtB, bself, out);
}

// Round 2
// 120.742 us; speedup vs baseline: 1.0417x; 1.0417x over previous
//
#include <hip/hip_runtime.h>
#include <math.h>

#define N_ATOMS    30000
#define N_PAIRS    300000
#define CAP        48              // bucket capacity per atom; multiple of 16
#define NF         64
#define ND         20
#define K_ENV      1280            // 20nu * 64f (packed, no padding)
#define K_TOT      1344            // K_ENV + 64 self features
#define NKSTEP     42              // K_TOT / 32
#define HARD_CUT   6.5f
#define BA         16              // atoms per block in main kernel
#define ESTRIDE    1352            // env row stride in u16 (1344+8 pad -> bank spread)
#define NM1        ((unsigned)(N_ATOMS - 1))

// inverse-distance quantization: invd in [1/6.5, 1/0.85] -> u16
#define INVD_LO    0.15384615385f
#define INVD_RANGE 1.02262443439f
#define QS         (65535.0f / INVD_RANGE)
#define DQ         (INVD_RANGE / 65535.0f)
#define NEXP2      (-0.7213475204444817f)   // -0.5 * log2(e)

typedef short    s16x8  __attribute__((ext_vector_type(8)));
typedef __bf16   bf16x8 __attribute__((ext_vector_type(8)));
typedef unsigned u32x4  __attribute__((ext_vector_type(4)));
typedef float    f32x4  __attribute__((ext_vector_type(4)));
typedef float    f32x16 __attribute__((ext_vector_type(16)));

typedef __attribute__((address_space(1))) const void gconst_void;
typedef __attribute__((address_space(3))) void       lds_void;

__device__ __forceinline__ unsigned short f2bf(float x) {
    union { float f; unsigned u; } v; v.f = x;
    unsigned r = v.u + 0x7fffu + ((v.u >> 16) & 1u);   // RNE
    return (unsigned short)(r >> 16);
}
// pack two floats -> packed bf16 pair (a in low 16), RNE
__device__ __forceinline__ unsigned pkbf(float a, float b) {
    return (unsigned)f2bf(a) | ((unsigned)f2bf(b) << 16);
}
// sensitivity for one packed pair-slot, lane's nu.
// w0 = second<<16 | invd_u16 ; lcb = bits of log2(cut) (f32).
// gauss*cut = exp2(-0.5*log2e*z^2 + log2(cut)) -- single transcendental.
__device__ __forceinline__ float senseval(unsigned w0, unsigned lcb, int kidx, int cnt,
                                          float zA, float zB, bool nuok) {
    float uu = (float)(w0 & 0xffffu);
    float z  = __builtin_fmaf(uu, zA, zB);            // z = invd*isig - musig
    float ar = __builtin_fmaf(z * z, NEXP2, __uint_as_float(lcb));
    float e  = __builtin_amdgcn_exp2f(ar);
    return (nuok && kidx < cnt) ? e : 0.0f;           // garbage slots (poison) -> 0
}

// ---------------------------------------------------------------------------
// K0: prep = pack weights into bf16 B-frag layout with phase-1 k'-permutation
// (blocks 0..41), zero cnts (42..159), msr (160), x -> packed-bf16 table
// (161..1098): xb16[a*32+c] = bf16(x[a,2c+1])<<16 | bf16(x[a,2c]).
// Weight perm (verified R9): k'<1280: t=k'/640, g=(k'%640)>>7, c=(k'&127)>>2,
// r=k'&3 -> nu=4g+r, f=2c+t ; k'>=1280: self row, f=k'-1280.
__global__ void k_prep(const float* __restrict__ iw, const float* __restrict__ wself,
                       const float* __restrict__ mu, const float* __restrict__ sigma,
                       const float* __restrict__ x,
                       unsigned short* __restrict__ WtB, int* __restrict__ cnts,
                       float2* __restrict__ msr, unsigned* __restrict__ xb16) {
    if (blockIdx.x < 42) {
        int idx = blockIdx.x * 256 + threadIdx.x;       // (ks*4+q)*64 + lane
        if (idx >= NKSTEP * 4 * 64) return;
        int l  = idx & 63;
        int q  = (idx >> 6) & 3;
        int ks = idx >> 8;
        int n  = q * 16 + (l & 15);
        int kb = ks * 32 + (l >> 4) * 8;
        u32x4 u;
        #pragma unroll
        for (int jj = 0; jj < 4; jj++) {
            unsigned short lo, hi;
            #pragma unroll
            for (int e = 0; e < 2; e++) {
                int k = kb + 2 * jj + e;
                float val;
                if (k < K_ENV) {
                    int t  = k / 640;
                    int rm = k - t * 640;
                    int g  = rm >> 7;
                    int c  = (rm & 127) >> 2;
                    int r  = k & 3;
                    int nu = 4 * g + r;
                    int f  = 2 * c + t;                  // even/odd tile split
                    val = iw[(nu * NF + n) * NF + f];
                } else {
                    val = wself[n * NF + (k - K_ENV)];
                }
                if (e == 0) lo = f2bf(val); else hi = f2bf(val);
            }
            u[jj] = (unsigned)lo | ((unsigned)hi << 16);
        }
        *(u32x4*)&WtB[idx * 8] = u;
    } else if (blockIdx.x < 160) {
        int i = (blockIdx.x - 42) * 256 + threadIdx.x;
        if (i < N_ATOMS) cnts[i] = 0;
    } else if (blockIdx.x == 160) {
        int i = threadIdx.x;
        if (i < ND) { float2 m; m.x = mu[i]; m.y = 1.0f / sigma[i]; msr[i] = m; }
    } else {
        int o = (blockIdx.x - 161) * 256 + threadIdx.x;  // uint4 of xb16
        if (o < N_ATOMS * 32 / 4) {
            int wbase = o * 4;                           // word wi covers floats 2wi,2wi+1
            const float* src = &x[(size_t)wbase * 2];
            float2 f0 = *(const float2*)(src);
            float2 f1 = *(const float2*)(src + 2);
            float2 f2 = *(const float2*)(src + 4);
            float2 f3 = *(const float2*)(src + 6);
            u32x4 u;
            u[0] = pkbf(f0.x, f0.y);
            u[1] = pkbf(f1.x, f1.y);
            u[2] = pkbf(f2.x, f2.y);
            u[3] = pkbf(f3.x, f3.y);
            *(u32x4*)&xb16[wbase] = u;
        }
    }
}

// ---------------------------------------------------------------------------
// K1: scatter pairs into per-atom buckets. Payload 8B/pair:
//   word0 = second<<16 | invd_u16  (inverse distance quantized -> no rcp in K2)
//   word1 = f32 bits of log2(cut(d)) computed ONCE per pair from exact d.
__global__ void k_scatter(const int* __restrict__ first, const int* __restrict__ second,
                          const float* __restrict__ dist, int* __restrict__ cnts,
                          uint2* __restrict__ pk) {
    int p = (blockIdx.x * 256 + threadIdx.x) * 2;
    if (p >= N_PAIRS) return;
    int2   f2 = *(const int2*)&first[p];
    int2   s2 = *(const int2*)&second[p];
    float2 d2 = *(const float2*)&dist[p];
    {
        float d    = d2.x;
        float invd = 1.0f / d;
        float tq   = fmaxf((invd - INVD_LO) * QS + 0.5f, 0.0f);
        unsigned u = min((unsigned)tq, 65535u);
        float co   = __cosf(0.2416609733530613f * d);    // 0.5*pi/6.5
        float lc   = fmaxf(__log2f(co * co), -10000.0f); // log2(cut); clamp -inf
        int pos = atomicAdd(&cnts[f2.x], 1);
        if (pos < CAP) {
            uint2 v; v.x = ((unsigned)s2.x << 16) | u; v.y = __float_as_uint(lc);
            pk[(size_t)f2.x * CAP + pos] = v;
        }
    }
    {
        float d    = d2.y;
        float invd = 1.0f / d;
        float tq   = fmaxf((invd - INVD_LO) * QS + 0.5f, 0.0f);
        unsigned u = min((unsigned)tq, 65535u);
        float co   = __cosf(0.2416609733530613f * d);
        float lc   = fmaxf(__log2f(co * co), -10000.0f);
        int pos = atomicAdd(&cnts[f2.y], 1);
        if (pos < CAP) {
            uint2 v; v.x = ((unsigned)s2.y << 16) | u; v.y = __float_as_uint(lc);
            pk[(size_t)f2.y * CAP + pos] = v;
        }
    }
}

// ---------------------------------------------------------------------------
// K2: fused sense + MFMA envsum + MFMA interaction matmul. 512 thr = 8 waves.
// R13: (a) block's pk slab (6KB) staged to LDS via global_load_lds up front ->
// phase-1 K-step chain starts from a ~40cy broadcast ds_read instead of a
// ~300cy L2 load. (b) phase-2 WtB loads 2-deep explicit prefetch, first two
// issued BEFORE the barrier (static addresses -> fly during barrier wait).
__global__ void __launch_bounds__(512, 6)
k_main(const unsigned* __restrict__ xb16, const int* __restrict__ cnts,
       const uint2* __restrict__ pk, const float2* __restrict__ msr,
       const unsigned short* __restrict__ WtB, const float* __restrict__ bself,
       float* __restrict__ out) {
    __shared__ unsigned short env[BA * ESTRIDE];          // 43264 B
    __shared__ uint2 pkl[BA * CAP];                       // 6144 B -> 49408 B total
    const int t  = threadIdx.x;
    const int w  = t >> 6;       // wave 0..7
    const int l  = t & 63;       // lane
    const int h  = l >> 5;       // half-wave (k-group)
    const int cl = l & 31;       // A: nu row   |  B/C: column
    const int a0 = blockIdx.x * BA;

    // stage this block's pk slab: 16 atoms x CAP x 8B = 6144B, 1KB per wave
    if (w < 6) {
        const char* gsrc = (const char*)(pk + (size_t)a0 * CAP) + (w * 64 + l) * 16;
        char* ldst = (char*)pkl + w * 1024;               // wave-uniform base
        __builtin_amdgcn_global_load_lds((gconst_void*)gsrc, (lds_void*)ldst, 16, 0, 0);
    }

    // lane-resident sense constants (nu = cl)
    float2 ms   = msr[min(cl, ND - 1)];
    const float isig = ms.y;
    const float zA   = DQ * isig;                         // z = u*zA + zB
    const float zB   = INVD_LO * isig - ms.x * isig;
    const bool  nuok = (cl < ND);
    const unsigned* xw = xb16 + cl;                       // lane's word column

    // hoist both atoms' counts -> the two dependent scalar chains overlap
    const int cntA = min(cnts[a0 + 2 * w + 0], CAP);
    const int cntB = min(cnts[a0 + 2 * w + 1], CAP);

    __syncthreads();                                      // pkl ready

    // ---- Phase 1: MFMA envsum (2 atoms per wave, sequential) ----
    #pragma unroll 1
    for (int ci = 0; ci < 2; ci++) {
        const int i = 2 * w + ci;
        const int a = a0 + i;
        const int cnt = ci ? cntB : cntA;
        const int nst = max((cnt + 15) >> 4, 1);
        const uint2* gb = &pkl[i * CAP];
        f32x16 acc0 = {0.f}, acc1 = {0.f};
        #pragma unroll 1
        for (int ks = 0; ks < nst; ks++) {
            const int k0 = ks * 16 + h * 8;
            const uint2* bp = gb + k0;                    // LDS, h-uniform broadcast
            uint4 q0 = *(const uint4*)(bp + 0);           // slots k0+0, k0+1
            uint4 q1 = *(const uint4*)(bp + 2);           // slots k0+2, k0+3
            uint4 q2 = *(const uint4*)(bp + 4);
            uint4 q3 = *(const uint4*)(bp + 6);
            // 8 dword gathers of pre-packed bf16 pairs (feats {2cl,2cl+1})
            unsigned g0 = xw[min(q0.x >> 16, NM1) * 32];
            unsigned g1 = xw[min(q0.z >> 16, NM1) * 32];
            unsigned g2 = xw[min(q1.x >> 16, NM1) * 32];
            unsigned g3 = xw[min(q1.z >> 16, NM1) * 32];
            unsigned g4 = xw[min(q2.x >> 16, NM1) * 32];
            unsigned g5 = xw[min(q2.z >> 16, NM1) * 32];
            unsigned g6 = xw[min(q3.x >> 16, NM1) * 32];
            unsigned g7 = xw[min(q3.z >> 16, NM1) * 32];
            u32x4 A, B0, B1;
            A[0] = pkbf(senseval(q0.x, q0.y, k0 + 0, cnt, zA, zB, nuok),
                        senseval(q0.z, q0.w, k0 + 1, cnt, zA, zB, nuok));
            A[1] = pkbf(senseval(q1.x, q1.y, k0 + 2, cnt, zA, zB, nuok),
                        senseval(q1.z, q1.w, k0 + 3, cnt, zA, zB, nuok));
            A[2] = pkbf(senseval(q2.x, q2.y, k0 + 4, cnt, zA, zB, nuok),
                        senseval(q2.z, q2.w, k0 + 5, cnt, zA, zB, nuok));
            A[3] = pkbf(senseval(q3.x, q3.y, k0 + 6, cnt, zA, zB, nuok),
                        senseval(q3.z, q3.w, k0 + 7, cnt, zA, zB, nuok));
            // v_perm lane-combines: low halves = even feats, high = odd feats
            B0[0] = __builtin_amdgcn_perm(g1, g0, 0x05040100u);
            B0[1] = __builtin_amdgcn_perm(g3, g2, 0x05040100u);
            B0[2] = __builtin_amdgcn_perm(g5, g4, 0x05040100u);
            B0[3] = __builtin_amdgcn_perm(g7, g6, 0x05040100u);
            B1[0] = __builtin_amdgcn_perm(g1, g0, 0x07060302u);
            B1[1] = __builtin_amdgcn_perm(g3, g2, 0x07060302u);
            B1[2] = __builtin_amdgcn_perm(g5, g4, 0x07060302u);
            B1[3] = __builtin_amdgcn_perm(g7, g6, 0x07060302u);
            acc0 = __builtin_amdgcn_mfma_f32_32x32x16_bf16(
                       __builtin_bit_cast(bf16x8, A),
                       __builtin_bit_cast(bf16x8, B0), acc0, 0, 0, 0);
            acc1 = __builtin_amdgcn_mfma_f32_32x32x16_bf16(
                       __builtin_bit_cast(bf16x8, A),
                       __builtin_bit_cast(bf16x8, B1), acc1, 0, 0, 0);
        }
        // C -> env LDS. C row = (reg&3)+8*(reg>>2)+4*h; g=2q+h holds rows
        // 4g..4g+3 (g<5 <=> row<20). k' = t*640 + g*128 + cl*4 + r.
        unsigned short* er = &env[i * ESTRIDE];
        #pragma unroll
        for (int q = 0; q < 3; q++) {
            int g = 2 * q + h;
            if (g < 5) {
                uint2 v0, v1;
                v0.x = pkbf(acc0[4 * q + 0], acc0[4 * q + 1]);
                v0.y = pkbf(acc0[4 * q + 2], acc0[4 * q + 3]);
                v1.x = pkbf(acc1[4 * q + 0], acc1[4 * q + 1]);
                v1.y = pkbf(acc1[4 * q + 2], acc1[4 * q + 3]);
                *(uint2*)&er[g * 128 + cl * 4]       = v0;
                *(uint2*)&er[640 + g * 128 + cl * 4] = v1;
            }
        }
        // self features (k'=1280..1343), from the bf16 table
        unsigned sw = xb16[(size_t)a * 32 + (l >> 1)];
        er[K_ENV + l] = (unsigned short)(sw >> ((l & 1) * 16));
    }

    // phase-2 prefetch: first two WtB frags + bias, issued before the barrier
    // (static addresses; loads fly while waiting on phase-1 laggards)
    const unsigned short* wb = &WtB[(w * 64 + l) * 8];    // ks-stride = 2048 shorts
    s16x8 b0, b1;
    float bs = 0.f;
    if (w < 4) {
        b0 = *(const s16x8*)(wb);
        b1 = *(const s16x8*)(wb + 2048);
        bs = bself[w * 16 + (l & 15)];
    }
    __syncthreads();                                      // env ready

    // ---- Phase 2: MFMA GEMM (waves 0..3), 2-deep bfrag pipeline ----
    if (w < 4) {
        const int m16  = l & 15;     // atom row / out col
        const int quad = l >> 4;
        f32x4 acc = {0.f, 0.f, 0.f, 0.f};
        for (int ks = 0; ks < NKSTEP; ks++) {
            s16x8 afrag = *(const s16x8*)&env[m16 * ESTRIDE + ks * 32 + quad * 8];
            s16x8 bcur = b0;
            b0 = b1;
            int nx = (ks + 2 < NKSTEP) ? ks + 2 : NKSTEP - 1;
            b1 = *(const s16x8*)(wb + (size_t)nx * 2048);
            acc = __builtin_amdgcn_mfma_f32_16x16x32_bf16(
                      __builtin_bit_cast(bf16x8, afrag),
                      __builtin_bit_cast(bf16x8, bcur), acc, 0, 0, 0);
        }
        #pragma unroll
        for (int r = 0; r < 4; r++) {
            int row = quad * 4 + r;                       // atom within block
            out[(size_t)(a0 + row) * NF + w * 16 + m16] = acc[r] + bs;
        }
    }
}

// ---------------------------------------------------------------------------
extern "C" void kernel_launch(void* const* d_in, const int* in_sizes, int n_in,
                              void* d_out, int out_size, void* d_ws, size_t ws_size,
                              hipStream_t stream) {
    const float* x      = (const float*)d_in[0];
    const int*   first  = (const int*)d_in[1];
    const int*   second = (const int*)d_in[2];
    const float* dist   = (const float*)d_in[3];
    const float* mu     = (const float*)d_in[4];
    const float* sigma  = (const float*)d_in[5];
    const float* iw     = (const float*)d_in[6];
    const float* wself  = (const float*)d_in[7];
    const float* bself  = (const float*)d_in[8];
    float* out = (float*)d_out;

    char* ws = (char*)d_ws;
    unsigned short* WtB  = (unsigned short*)(ws);          // 172032 B
    int*            cnts = (int*)(ws + 172032);            // 120000 B
    float2*         msr  = (float2*)(ws + 292032);         // 160 B
    uint2*          pk   = (uint2*)(ws + 292192);          // 11520000 B
    unsigned*       xb16 = (unsigned*)(ws + 11812192);     // 3840000 B -> ~15.7 MB

    k_prep<<<dim3(161 + (N_ATOMS * 8 + 255) / 256), dim3(256), 0, stream>>>(
        iw, wself, mu, sigma, x, WtB, cnts, msr, xb16);
    k_scatter<<<dim3((N_PAIRS / 2 + 255) / 256), dim3(256), 0, stream>>>(
        first, second, dist, cnts, pk);
    k_main<<<dim3(N_ATOMS / BA), dim3(512), 0, stream>>>(
        xb16, cnts, pk, msr, WtB, bself, out);
}

// Round 3
// 118.845 us; speedup vs baseline: 1.0583x; 1.0160x over previous
//
#include <hip/hip_runtime.h>
#include <math.h>

#define N_ATOMS    30000
#define N_PAIRS    300000
#define CAP        48              // bucket capacity per atom; multiple of 16
#define NF         64
#define ND         20
#define K_ENV      1280            // 20nu * 64f (packed, no padding)
#define K_TOT      1344            // K_ENV + 64 self features
#define NKSTEP     42              // K_TOT / 32
#define KSH        21              // NKSTEP / 2 (per-wave K half in phase 2)
#define HARD_CUT   6.5f
#define BA         16              // atoms per block in main kernel
#define ESTRIDE    1352            // env row stride in u16 (1344+8 pad -> bank spread)
#define NM1        ((unsigned)(N_ATOMS - 1))

// inverse-distance quantization: invd in [1/6.5, 1/0.85] -> u16
#define INVD_LO    0.15384615385f
#define INVD_RANGE 1.02262443439f
#define QS         (65535.0f / INVD_RANGE)
#define DQ         (INVD_RANGE / 65535.0f)
#define NEXP2      (-0.7213475204444817f)   // -0.5 * log2(e)

typedef short    s16x8  __attribute__((ext_vector_type(8)));
typedef __bf16   bf16x8 __attribute__((ext_vector_type(8)));
typedef unsigned u32x4  __attribute__((ext_vector_type(4)));
typedef float    f32x4  __attribute__((ext_vector_type(4)));
typedef float    f32x16 __attribute__((ext_vector_type(16)));

typedef __attribute__((address_space(1))) const void gconst_void;
typedef __attribute__((address_space(3))) void       lds_void;

__device__ __forceinline__ unsigned short f2bf(float x) {
    union { float f; unsigned u; } v; v.f = x;
    unsigned r = v.u + 0x7fffu + ((v.u >> 16) & 1u);   // RNE
    return (unsigned short)(r >> 16);
}
// pack two floats -> packed bf16 pair (a in low 16), RNE
__device__ __forceinline__ unsigned pkbf(float a, float b) {
    return (unsigned)f2bf(a) | ((unsigned)f2bf(b) << 16);
}
// sensitivity for one packed pair-slot, lane's nu.
// w0 = second<<16 | invd_u16 ; lcb = bits of log2(cut) (f32).
// gauss*cut = exp2(-0.5*log2e*z^2 + log2(cut)) -- single transcendental.
__device__ __forceinline__ float senseval(unsigned w0, unsigned lcb, int kidx, int cnt,
                                          float zA, float zB, bool nuok) {
    float uu = (float)(w0 & 0xffffu);
    float z  = __builtin_fmaf(uu, zA, zB);            // z = invd*isig - musig
    float ar = __builtin_fmaf(z * z, NEXP2, __uint_as_float(lcb));
    float e  = __builtin_amdgcn_exp2f(ar);
    return (nuok && kidx < cnt) ? e : 0.0f;           // garbage slots (poison) -> 0
}

// ---------------------------------------------------------------------------
// K0: prep = pack weights into bf16 B-frag layout with phase-1 k'-permutation
// (blocks 0..41), zero cnts (42..159), msr (160), x -> packed-bf16 table
// (161..1098): xb16[a*32+c] = bf16(x[a,2c+1])<<16 | bf16(x[a,2c]).
// Weight perm (verified R9): k'<1280: t=k'/640, g=(k'%640)>>7, c=(k'&127)>>2,
// r=k'&3 -> nu=4g+r, f=2c+t ; k'>=1280: self row, f=k'-1280.
__global__ void k_prep(const float* __restrict__ iw, const float* __restrict__ wself,
                       const float* __restrict__ mu, const float* __restrict__ sigma,
                       const float* __restrict__ x,
                       unsigned short* __restrict__ WtB, int* __restrict__ cnts,
                       float2* __restrict__ msr, unsigned* __restrict__ xb16) {
    if (blockIdx.x < 42) {
        int idx = blockIdx.x * 256 + threadIdx.x;       // (ks*4+q)*64 + lane
        if (idx >= NKSTEP * 4 * 64) return;
        int l  = idx & 63;
        int q  = (idx >> 6) & 3;
        int ks = idx >> 8;
        int n  = q * 16 + (l & 15);
        int kb = ks * 32 + (l >> 4) * 8;
        u32x4 u;
        #pragma unroll
        for (int jj = 0; jj < 4; jj++) {
            unsigned short lo, hi;
            #pragma unroll
            for (int e = 0; e < 2; e++) {
                int k = kb + 2 * jj + e;
                float val;
                if (k < K_ENV) {
                    int t  = k / 640;
                    int rm = k - t * 640;
                    int g  = rm >> 7;
                    int c  = (rm & 127) >> 2;
                    int r  = k & 3;
                    int nu = 4 * g + r;
                    int f  = 2 * c + t;                  // even/odd tile split
                    val = iw[(nu * NF + n) * NF + f];
                } else {
                    val = wself[n * NF + (k - K_ENV)];
                }
                if (e == 0) lo = f2bf(val); else hi = f2bf(val);
            }
            u[jj] = (unsigned)lo | ((unsigned)hi << 16);
        }
        *(u32x4*)&WtB[idx * 8] = u;
    } else if (blockIdx.x < 160) {
        int i = (blockIdx.x - 42) * 256 + threadIdx.x;
        if (i < N_ATOMS) cnts[i] = 0;
    } else if (blockIdx.x == 160) {
        int i = threadIdx.x;
        if (i < ND) { float2 m; m.x = mu[i]; m.y = 1.0f / sigma[i]; msr[i] = m; }
    } else {
        int o = (blockIdx.x - 161) * 256 + threadIdx.x;  // uint4 of xb16
        if (o < N_ATOMS * 32 / 4) {
            int wbase = o * 4;                           // word wi covers floats 2wi,2wi+1
            const float* src = &x[(size_t)wbase * 2];
            float2 f0 = *(const float2*)(src);
            float2 f1 = *(const float2*)(src + 2);
            float2 f2 = *(const float2*)(src + 4);
            float2 f3 = *(const float2*)(src + 6);
            u32x4 u;
            u[0] = pkbf(f0.x, f0.y);
            u[1] = pkbf(f1.x, f1.y);
            u[2] = pkbf(f2.x, f2.y);
            u[3] = pkbf(f3.x, f3.y);
            *(u32x4*)&xb16[wbase] = u;
        }
    }
}

// ---------------------------------------------------------------------------
// K1: scatter pairs into per-atom buckets. Payload 8B/pair:
//   word0 = second<<16 | invd_u16  (inverse distance quantized -> no rcp in K2)
//   word1 = f32 bits of log2(cut(d)) computed ONCE per pair from exact d.
__global__ void k_scatter(const int* __restrict__ first, const int* __restrict__ second,
                          const float* __restrict__ dist, int* __restrict__ cnts,
                          uint2* __restrict__ pk) {
    int p = (blockIdx.x * 256 + threadIdx.x) * 2;
    if (p >= N_PAIRS) return;
    int2   f2 = *(const int2*)&first[p];
    int2   s2 = *(const int2*)&second[p];
    float2 d2 = *(const float2*)&dist[p];
    {
        float d    = d2.x;
        float invd = 1.0f / d;
        float tq   = fmaxf((invd - INVD_LO) * QS + 0.5f, 0.0f);
        unsigned u = min((unsigned)tq, 65535u);
        float co   = __cosf(0.2416609733530613f * d);    // 0.5*pi/6.5
        float lc   = fmaxf(__log2f(co * co), -10000.0f); // log2(cut); clamp -inf
        int pos = atomicAdd(&cnts[f2.x], 1);
        if (pos < CAP) {
            uint2 v; v.x = ((unsigned)s2.x << 16) | u; v.y = __float_as_uint(lc);
            pk[(size_t)f2.x * CAP + pos] = v;
        }
    }
    {
        float d    = d2.y;
        float invd = 1.0f / d;
        float tq   = fmaxf((invd - INVD_LO) * QS + 0.5f, 0.0f);
        unsigned u = min((unsigned)tq, 65535u);
        float co   = __cosf(0.2416609733530613f * d);
        float lc   = fmaxf(__log2f(co * co), -10000.0f);
        int pos = atomicAdd(&cnts[f2.y], 1);
        if (pos < CAP) {
            uint2 v; v.x = ((unsigned)s2.y << 16) | u; v.y = __float_as_uint(lc);
            pk[(size_t)f2.y * CAP + pos] = v;
        }
    }
}

// ---------------------------------------------------------------------------
// K2: fused sense + MFMA envsum + MFMA interaction matmul. 512 thr = 8 waves.
// R13: pk slab (6KB) staged to LDS via global_load_lds up front.
// R14: phase-2 split across ALL 8 waves (wave w: quadrant w&3, K-half w>>2,
// 21 ks each; waves 4-7 dump partial acc to LDS (reusing pkl), waves 0-3
// reduce+store) + 4-deep b-frag prefetch issued before the env barrier.
__global__ void __launch_bounds__(512, 6)
k_main(const unsigned* __restrict__ xb16, const int* __restrict__ cnts,
       const uint2* __restrict__ pk, const float2* __restrict__ msr,
       const unsigned short* __restrict__ WtB, const float* __restrict__ bself,
       float* __restrict__ out) {
    __shared__ unsigned short env[BA * ESTRIDE];          // 43264 B
    __shared__ uint2 pkl[BA * CAP];                       // 6144 B -> 49408 B total
    const int t  = threadIdx.x;
    const int w  = t >> 6;       // wave 0..7
    const int l  = t & 63;       // lane
    const int h  = l >> 5;       // half-wave (k-group)
    const int cl = l & 31;       // A: nu row   |  B/C: column
    const int a0 = blockIdx.x * BA;

    // stage this block's pk slab: 16 atoms x CAP x 8B = 6144B, 1KB per wave
    if (w < 6) {
        const char* gsrc = (const char*)(pk + (size_t)a0 * CAP) + (w * 64 + l) * 16;
        char* ldst = (char*)pkl + w * 1024;               // wave-uniform base
        __builtin_amdgcn_global_load_lds((gconst_void*)gsrc, (lds_void*)ldst, 16, 0, 0);
    }

    // lane-resident sense constants (nu = cl)
    float2 ms   = msr[min(cl, ND - 1)];
    const float isig = ms.y;
    const float zA   = DQ * isig;                         // z = u*zA + zB
    const float zB   = INVD_LO * isig - ms.x * isig;
    const bool  nuok = (cl < ND);
    const unsigned* xw = xb16 + cl;                       // lane's word column

    // hoist both atoms' counts -> the two dependent scalar chains overlap
    const int cntA = min(cnts[a0 + 2 * w + 0], CAP);
    const int cntB = min(cnts[a0 + 2 * w + 1], CAP);

    __syncthreads();                                      // pkl ready

    // ---- Phase 1: MFMA envsum (2 atoms per wave, sequential) ----
    #pragma unroll 1
    for (int ci = 0; ci < 2; ci++) {
        const int i = 2 * w + ci;
        const int a = a0 + i;
        const int cnt = ci ? cntB : cntA;
        const int nst = max((cnt + 15) >> 4, 1);
        const uint2* gb = &pkl[i * CAP];
        f32x16 acc0 = {0.f}, acc1 = {0.f};
        #pragma unroll 1
        for (int ks = 0; ks < nst; ks++) {
            const int k0 = ks * 16 + h * 8;
            const uint2* bp = gb + k0;                    // LDS, h-uniform broadcast
            uint4 q0 = *(const uint4*)(bp + 0);           // slots k0+0, k0+1
            uint4 q1 = *(const uint4*)(bp + 2);           // slots k0+2, k0+3
            uint4 q2 = *(const uint4*)(bp + 4);
            uint4 q3 = *(const uint4*)(bp + 6);
            // 8 dword gathers of pre-packed bf16 pairs (feats {2cl,2cl+1})
            unsigned g0 = xw[min(q0.x >> 16, NM1) * 32];
            unsigned g1 = xw[min(q0.z >> 16, NM1) * 32];
            unsigned g2 = xw[min(q1.x >> 16, NM1) * 32];
            unsigned g3 = xw[min(q1.z >> 16, NM1) * 32];
            unsigned g4 = xw[min(q2.x >> 16, NM1) * 32];
            unsigned g5 = xw[min(q2.z >> 16, NM1) * 32];
            unsigned g6 = xw[min(q3.x >> 16, NM1) * 32];
            unsigned g7 = xw[min(q3.z >> 16, NM1) * 32];
            u32x4 A, B0, B1;
            A[0] = pkbf(senseval(q0.x, q0.y, k0 + 0, cnt, zA, zB, nuok),
                        senseval(q0.z, q0.w, k0 + 1, cnt, zA, zB, nuok));
            A[1] = pkbf(senseval(q1.x, q1.y, k0 + 2, cnt, zA, zB, nuok),
                        senseval(q1.z, q1.w, k0 + 3, cnt, zA, zB, nuok));
            A[2] = pkbf(senseval(q2.x, q2.y, k0 + 4, cnt, zA, zB, nuok),
                        senseval(q2.z, q2.w, k0 + 5, cnt, zA, zB, nuok));
            A[3] = pkbf(senseval(q3.x, q3.y, k0 + 6, cnt, zA, zB, nuok),
                        senseval(q3.z, q3.w, k0 + 7, cnt, zA, zB, nuok));
            // v_perm lane-combines: low halves = even feats, high = odd feats
            B0[0] = __builtin_amdgcn_perm(g1, g0, 0x05040100u);
            B0[1] = __builtin_amdgcn_perm(g3, g2, 0x05040100u);
            B0[2] = __builtin_amdgcn_perm(g5, g4, 0x05040100u);
            B0[3] = __builtin_amdgcn_perm(g7, g6, 0x05040100u);
            B1[0] = __builtin_amdgcn_perm(g1, g0, 0x07060302u);
            B1[1] = __builtin_amdgcn_perm(g3, g2, 0x07060302u);
            B1[2] = __builtin_amdgcn_perm(g5, g4, 0x07060302u);
            B1[3] = __builtin_amdgcn_perm(g7, g6, 0x07060302u);
            acc0 = __builtin_amdgcn_mfma_f32_32x32x16_bf16(
                       __builtin_bit_cast(bf16x8, A),
                       __builtin_bit_cast(bf16x8, B0), acc0, 0, 0, 0);
            acc1 = __builtin_amdgcn_mfma_f32_32x32x16_bf16(
                       __builtin_bit_cast(bf16x8, A),
                       __builtin_bit_cast(bf16x8, B1), acc1, 0, 0, 0);
        }
        // C -> env LDS. C row = (reg&3)+8*(reg>>2)+4*h; g=2q+h holds rows
        // 4g..4g+3 (g<5 <=> row<20). k' = t*640 + g*128 + cl*4 + r.
        unsigned short* er = &env[i * ESTRIDE];
        #pragma unroll
        for (int q = 0; q < 3; q++) {
            int g = 2 * q + h;
            if (g < 5) {
                uint2 v0, v1;
                v0.x = pkbf(acc0[4 * q + 0], acc0[4 * q + 1]);
                v0.y = pkbf(acc0[4 * q + 2], acc0[4 * q + 3]);
                v1.x = pkbf(acc1[4 * q + 0], acc1[4 * q + 1]);
                v1.y = pkbf(acc1[4 * q + 2], acc1[4 * q + 3]);
                *(uint2*)&er[g * 128 + cl * 4]       = v0;
                *(uint2*)&er[640 + g * 128 + cl * 4] = v1;
            }
        }
        // self features (k'=1280..1343), from the bf16 table
        unsigned sw = xb16[(size_t)a * 32 + (l >> 1)];
        er[K_ENV + l] = (unsigned short)(sw >> ((l & 1) * 16));
    }

    // phase-2 prefetch (ALL waves): first four WtB frags + bias, issued
    // BEFORE the barrier (static addresses -> fly during phase-1 laggards).
    const int wq     = w & 3;             // output feature quadrant
    const int ksbase = (w >> 2) * KSH;    // K half: 0..20 or 21..41
    const unsigned short* wb = &WtB[((ksbase * 4 + wq) * 64 + l) * 8]; // ks-stride 2048
    s16x8 b0 = *(const s16x8*)(wb);
    s16x8 b1 = *(const s16x8*)(wb + 2048);
    s16x8 b2 = *(const s16x8*)(wb + 4096);
    s16x8 b3 = *(const s16x8*)(wb + 6144);
    float bs = (w < 4) ? bself[wq * 16 + (l & 15)] : 0.f;
    __syncthreads();                                      // env ready (pkl now dead)

    // ---- Phase 2: MFMA GEMM, all 8 waves, 21 ks each, 4-deep pipeline ----
    {
        const int m16  = l & 15;     // atom row / out col
        const int quad = l >> 4;
        f32x4 acc = {0.f, 0.f, 0.f, 0.f};
        for (int kk = 0; kk < KSH; kk++) {
            int ks = ksbase + kk;
            s16x8 afrag = *(const s16x8*)&env[m16 * ESTRIDE + ks * 32 + quad * 8];
            s16x8 bcur = b0;
            b0 = b1; b1 = b2; b2 = b3;
            int nx = (kk + 4 < KSH) ? kk + 4 : KSH - 1;
            b3 = *(const s16x8*)(wb + (size_t)nx * 2048);
            acc = __builtin_amdgcn_mfma_f32_16x16x32_bf16(
                      __builtin_bit_cast(bf16x8, afrag),
                      __builtin_bit_cast(bf16x8, bcur), acc, 0, 0, 0);
        }
        // cross-wave K reduction through LDS (reuse pkl: 4096B needed < 6144B)
        float* red = (float*)pkl;
        if (w >= 4) {
            *(f32x4*)&red[((w - 4) * 64 + l) * 4] = acc;
        }
        __syncthreads();
        if (w < 4) {
            f32x4 other = *(const f32x4*)&red[(w * 64 + l) * 4];
            #pragma unroll
            for (int r = 0; r < 4; r++) {
                int row = quad * 4 + r;                   // atom within block
                out[(size_t)(a0 + row) * NF + wq * 16 + m16] = acc[r] + other[r] + bs;
            }
        }
    }
}

// ---------------------------------------------------------------------------
extern "C" void kernel_launch(void* const* d_in, const int* in_sizes, int n_in,
                              void* d_out, int out_size, void* d_ws, size_t ws_size,
                              hipStream_t stream) {
    const float* x      = (const float*)d_in[0];
    const int*   first  = (const int*)d_in[1];
    const int*   second = (const int*)d_in[2];
    const float* dist   = (const float*)d_in[3];
    const float* mu     = (const float*)d_in[4];
    const float* sigma  = (const float*)d_in[5];
    const float* iw     = (const float*)d_in[6];
    const float* wself  = (const float*)d_in[7];
    const float* bself  = (const float*)d_in[8];
    float* out = (float*)d_out;

    char* ws = (char*)d_ws;
    unsigned short* WtB  = (unsigned short*)(ws);          // 172032 B
    int*            cnts = (int*)(ws + 172032);            // 120000 B
    float2*         msr  = (float2*)(ws + 292032);         // 160 B
    uint2*          pk   = (uint2*)(ws + 292192);          // 11520000 B
    unsigned*       xb16 = (unsigned*)(ws + 11812192);     // 3840000 B -> ~15.7 MB

    k_prep<<<dim3(161 + (N_ATOMS * 8 + 255) / 256), dim3(256), 0, stream>>>(
        iw, wself, mu, sigma, x, WtB, cnts, msr, xb16);
    k_scatter<<<dim3((N_PAIRS / 2 + 255) / 256), dim3(256), 0, stream>>>(
        first, second, dist, cnts, pk);
    k_main<<<dim3(N_ATOMS / BA), dim3(512), 0, stream>>>(
        xb16, cnts, pk, msr, WtB, bself, out);
}